// Round 14
// baseline (422.297 us; speedup 1.0000x reference)
//
#include <hip/hip_runtime.h>
#include <hip/hip_fp16.h>
#include <cstdint>
#include <cstddef>

// Dims (fixed by the reference)
#define B_  4
#define S_  2048
#define D_  1024
#define H_  16
#define HD_ 64
#define TAU_ 0.125f
// TAU * log2(e), applied in f32 in the Q-projection epilogue (exp2 domain)
#define QSCALE_ 0.18033688011112042f

typedef _Float16 f16;
typedef __attribute__((ext_vector_type(8)))  _Float16 f16x8;
typedef __attribute__((ext_vector_type(4)))  _Float16 f16x4;
typedef __attribute__((ext_vector_type(2)))  __fp16   fp16x2_b;   // builtin ret type
typedef __attribute__((ext_vector_type(4)))  float    f32x4;
typedef __attribute__((ext_vector_type(16))) float    f32x16;
typedef __attribute__((ext_vector_type(2)))  unsigned u32x2;

// Async global->LDS, 16B per lane. LDS dest must be the WAVE-UNIFORM chunk
// base; HW writes lane l at base + l*16 (m97 pattern). Global addr is per-lane.
__device__ __forceinline__ void gload_lds16(const void* g, void* l) {
    __builtin_amdgcn_global_load_lds(
        (const __attribute__((address_space(1))) unsigned int*)g,
        (__attribute__((address_space(3)))       unsigned int*)l,
        16, 0, 0);
}

__device__ __forceinline__ unsigned pkh(float a, float b) {
    fp16x2_b h = __builtin_amdgcn_cvt_pkrtz(a, b);
    return __builtin_bit_cast(unsigned, h);
}

// raw v_exp_f32 = 2^x
__device__ __forceinline__ float exp2_hw(float x) {
    float r;
    asm("v_exp_f32 %0, %1" : "=v"(r) : "v"(x));
    return r;
}

__device__ __forceinline__ float max3f(float a, float b, float c) {
    float r;
    asm("v_max3_f32 %0, %1, %2, %3" : "=v"(r) : "v"(a), "v"(b), "v"(c));
    return r;
}

// permlane32_swap(x,x): {out0,out1} = {own,partner} (order differs per half),
// so max/sum over both gives the cross-half combine without a select.
__device__ __forceinline__ float pair_max(float x) {
    unsigned xu = __builtin_bit_cast(unsigned, x);
    u32x2 r = __builtin_amdgcn_permlane32_swap(xu, xu, false, false);
    return fmaxf(__builtin_bit_cast(float, r[0]), __builtin_bit_cast(float, r[1]));
}
__device__ __forceinline__ float pair_sum(float x) {
    unsigned xu = __builtin_bit_cast(unsigned, x);
    u32x2 r = __builtin_amdgcn_permlane32_swap(xu, xu, false, false);
    return __builtin_bit_cast(float, r[0]) + __builtin_bit_cast(float, r[1]);
}

// ---------------------------------------------------------------------------
// Mask normalization: detect physical dtype (bool bytes / int32 / float32)
// from the first 8192 bytes; write canonical bytes AND additive f32 bias.
// ---------------------------------------------------------------------------
__global__ __launch_bounds__(256) void mask_norm_kernel(
    const unsigned char* __restrict__ mp, unsigned char* __restrict__ nm,
    float* __restrict__ mf)
{
    __shared__ int flags[3];
    const int tid = threadIdx.x;
    if (tid < 3) flags[tid] = 0;
    __syncthreads();
    int loc0 = 0, loc1 = 0, loc2 = 0;
    for (int i = 0; i < 32; ++i) {
        int off = tid * 32 + i;
        unsigned char v = mp[off];
        if (v) {
            int m = off & 3;
            if (m == 0) loc0 = 1;
            else if (m == 1) loc1 = 1;
            else loc2 = 1;
        }
    }
    if (loc0) atomicOr(&flags[0], 1);
    if (loc1) atomicOr(&flags[1], 1);
    if (loc2) atomicOr(&flags[2], 1);
    __syncthreads();
    const int mode = flags[1] ? 0 : (flags[2] ? 2 : (flags[0] ? 1 : 0));
    for (int i = 0; i < 32; ++i) {
        int idx = tid * 32 + i;            // 8192 mask elements
        unsigned char r;
        if (mode == 0)      r = mp[idx] ? 1 : 0;
        else if (mode == 1) r = ((const int*)mp)[idx] ? 1 : 0;
        else                r = (((const float*)mp)[idx] != 0.f) ? 1 : 0;
        nm[idx] = r;
        mf[idx] = r ? -1e30f : 0.f;
    }
}

// ---------------------------------------------------------------------------
// W[k][n] fp32 -> Wt[n][k] fp16 (transpose via padded LDS tiles).
// ---------------------------------------------------------------------------
__global__ __launch_bounds__(256) void wconv_kernel(
    const float* __restrict__ W0, const float* __restrict__ W1,
    const float* __restrict__ W2, const float* __restrict__ W3,
    f16* __restrict__ Wt)
{
    __shared__ float T[64][65];
    const int z = blockIdx.z;
    const float* W = (z == 0) ? W0 : (z == 1) ? W1 : (z == 2) ? W2 : W3;
    f16* out = Wt + (size_t)z * D_ * D_;
    const int n0 = blockIdx.x * 64, k0 = blockIdx.y * 64;
    const int tid = threadIdx.x;
    for (int j = 0; j < 4; ++j) {
        int idx = j * 256 + tid;           // 1024 float4 chunks
        int r = idx >> 4, c4 = idx & 15;
        float4 v = *(const float4*)&W[(size_t)(k0 + r) * D_ + n0 + c4 * 4];
        T[r][c4 * 4 + 0] = v.x; T[r][c4 * 4 + 1] = v.y;
        T[r][c4 * 4 + 2] = v.z; T[r][c4 * 4 + 3] = v.w;
    }
    __syncthreads();
    for (int j = 0; j < 16; ++j) {
        int idx = j * 256 + tid;           // 4096 elems
        int nl = idx >> 6, kl = idx & 63;
        out[(size_t)(n0 + nl) * D_ + k0 + kl] = (f16)T[kl][nl];
    }
}

// ---------------------------------------------------------------------------
// FUSED QKV projection GEMM: ONE kernel, A-tile staged once per K-step and
// multiplied against Wq/Wk/Wv tiles (3x arithmetic intensity on A; 96 MFMA
// per barrier vs 32 -- r13 diagnosis: per-z kernels were latency-bound at
// 14-17% MfmaUtil with too little compute per staged byte).
// A fp32 reg-staged (float4 -> cvt -> swizzled ds_write, 16KB); Bq/Bk/Bv via
// global_load_lds (48KB). 64KB LDS single-buffered, serial 2-barrier loop.
// acc[3][4][4] = 192 VGPR; __launch_bounds__(256,2) grants 256-reg budget.
// Epilogues: z0 Q row-major *QSCALE, z1 K row-major, z2 V -> [b][h][hd][s].
// ---------------------------------------------------------------------------
__global__ __launch_bounds__(256, 2) void gemm_qkv_fused_kernel(
    const float* __restrict__ q, const float* __restrict__ k,
    const float* __restrict__ v, const f16* __restrict__ Wt,
    const float* __restrict__ bq, const float* __restrict__ bk,
    const float* __restrict__ bv, f16* __restrict__ outbase)
{
    __shared__ __align__(16) f16 Al[128 * 64];      // 16KB
    __shared__ __align__(16) f16 Bl[3][128 * 64];   // 48KB
    const float* A = q;                             // A shared by all three
    (void)k; (void)v;                               // (same tensor? no: q,k,v differ)
    const int m0 = blockIdx.x * 128, n0 = blockIdx.y * 128;
    const int tid = threadIdx.x, lane = tid & 63, wid = tid >> 6;
    const int wm = (wid >> 1) * 64, wn = (wid & 1) * 64;
    const int g = lane >> 4, c = lane & 15;

    // NOTE: q,k,v are DIFFERENT input tensors -- only the WEIGHTS differ per z
    // in the projection z-loop, but A differs too (q@Wq, k@Wk, v@Wv). Fusion
    // still pays because the three A-tiles come from three DIFFERENT tensors
    // at the same (m0,k0) -- stage all three? That would need 3x A LDS.
    // Instead: stage A_q, A_k, A_v interleaved is 48KB + 48KB B = 96KB > 64KB.
    // Resolution: B-tiles (weights, 2MB each) are L2-resident after first
    // use; A-tiles are the latency problem. We stage the three A-tiles
    // (3x16KB) and DMA the three B-tiles into ONE reused 16KB buffer per z?
    // -- can't: DMA per z must complete before its compute; that re-serializes.
    // FINAL LAYOUT: A_q/A_k/A_v in 48KB + one B tile 16KB, B re-staged per z
    // inside the K-step with its own mini-drain. B is L2-hot (re-read 64x),
    // so its DMA drain is ~200cyc, amortized over 32 MFMA each. A (the
    // HBM-latency operand) is staged once per K-step for all three GEMMs.
    __syncthreads();  // placeholder; real implementation below
}

// ---------------------------------------------------------------------------
// Actual fused QKV kernel (see analysis above): A_q/A_k/A_v staged per K-step
// (reg-cvt path, 48KB), single shared B buffer DMA'd per z (16KB), serial.
// ---------------------------------------------------------------------------
__global__ __launch_bounds__(256, 2) void gemm_qkv3_kernel(
    const float* __restrict__ q, const float* __restrict__ k,
    const float* __restrict__ v, const f16* __restrict__ Wt,
    const float* __restrict__ bq, const float* __restrict__ bk,
    const float* __restrict__ bv, f16* __restrict__ outbase)
{
    __shared__ __align__(16) f16 Al[3][128 * 64];   // 48KB
    __shared__ __align__(16) f16 Bl[128 * 64];      // 16KB
    const int m0 = blockIdx.x * 128, n0 = blockIdx.y * 128;
    const int tid = threadIdx.x, lane = tid & 63, wid = tid >> 6;
    const int wm = (wid >> 1) * 64, wn = (wid & 1) * 64;
    const int g = lane >> 4, c = lane & 15;

    f32x4 acc[3][4][4] = {};

    for (int kt = 0; kt < 16; ++kt) {
        const int k0 = kt * 64;
        // --- stage A_q, A_k, A_v: f32 load -> f16 cvt -> swizzled ds_write ---
        {
            const float* Az[3] = { q, k, v };
            #pragma unroll
            for (int z = 0; z < 3; ++z) {
                #pragma unroll
                for (int j = 0; j < 8; ++j) {
                    int idx = j * 256 + tid;           // 2048 float4 chunks
                    int row = idx >> 4, c4 = idx & 15;
                    float4 va = *(const float4*)&Az[z][(size_t)(m0 + row) * 1024 + k0 + c4 * 4];
                    f16x4 h;
                    h[0] = (f16)va.x; h[1] = (f16)va.y;
                    h[2] = (f16)va.z; h[3] = (f16)va.w;
                    int ps = (c4 >> 1) ^ (row & 7);
                    *(f16x4*)&Al[z][row * 64 + ps * 8 + (c4 & 1) * 4] = h;
                }
            }
        }
        // --- per z: DMA B tile, drain, 32 MFMA against shared-format A ---
        #pragma unroll
        for (int z = 0; z < 3; ++z) {
            // B DMA issued while previous z's MFMAs retire
            #pragma unroll
            for (int i = 0; i < 4; ++i) {
                int ch  = wid * 4 + i;                 // 16 chunks of 1024B
                int row = ch * 8 + (lane >> 3);
                int ls  = (lane & 7) ^ (row & 7);
                gload_lds16(Wt + (size_t)z * D_ * D_ + (size_t)(n0 + row) * 1024 + k0 + ls * 8,
                            Bl + ch * 512);
            }
            __syncthreads();                           // B ready; A ready (z=0)
            #pragma unroll
            for (int kc = 0; kc < 2; ++kc) {
                f16x8 af[4], bf[4];
                #pragma unroll
                for (int mb = 0; mb < 4; ++mb) {
                    int row = wm + mb * 16 + c;
                    af[mb] = *(const f16x8*)&Al[z][row * 64 + ((kc * 4 + g) ^ (row & 7)) * 8];
                }
                #pragma unroll
                for (int nb = 0; nb < 4; ++nb) {
                    int row = wn + nb * 16 + c;
                    bf[nb] = *(const f16x8*)&Bl[row * 64 + ((kc * 4 + g) ^ (row & 7)) * 8];
                }
                __builtin_amdgcn_s_setprio(1);
                #pragma unroll
                for (int mb = 0; mb < 4; ++mb)
                    #pragma unroll
                    for (int nb = 0; nb < 4; ++nb)
                        acc[z][mb][nb] = __builtin_amdgcn_mfma_f32_16x16x32_f16(
                            af[mb], bf[nb], acc[z][mb][nb], 0, 0, 0);
                __builtin_amdgcn_s_setprio(0);
            }
            __syncthreads();                           // B buffer free for next z
        }
    }

    // --- epilogues: C/D layout col=lane&15, row=(lane>>4)*4+reg (m89) ---
    #pragma unroll
    for (int z = 0; z < 3; ++z) {
        const float* bi = (z == 0) ? bq : (z == 1) ? bk : bv;
        f16* Cp = outbase + (size_t)z * S_ * B_ * D_;
        const float osc = (z == 0) ? QSCALE_ : 1.f;
        for (int nb = 0; nb < 4; ++nb) {
            int n = n0 + wn + nb * 16 + c;
            float bv2 = bi[n];
            for (int mb = 0; mb < 4; ++mb)
                for (int r = 0; r < 4; ++r) {
                    int m = m0 + wm + mb * 16 + g * 4 + r;
                    float val = (acc[z][mb][nb][r] + bv2) * osc;
                    if (z == 2) {
                        // [b][h][hd][s]  (b=m>>11, s=m&2047, h=n>>6, hd=n&63)
                        Cp[(((size_t)(m >> 11) * H_ + (n >> 6)) * HD_ + (n & 63)) * S_ + (m & 2047)] = (f16)val;
                    } else {
                        Cp[(size_t)m * 1024 + n] = (f16)val;
                    }
                }
        }
    }
}

// ---------------------------------------------------------------------------
// Output projection (r10 serial form): Oh (f16) @ Wo^T + bo -> fp32 out.
// f16 A via global_load_lds, 32KB LDS, 128x128 structure.
// ---------------------------------------------------------------------------
__global__ __launch_bounds__(256) void gemm_out_kernel(
    const f16* __restrict__ Oh, const f16* __restrict__ WtO,
    const float* __restrict__ bo, float* __restrict__ out)
{
    __shared__ __align__(16) f16 Al[128 * 64];
    __shared__ __align__(16) f16 Bl[128 * 64];
    const int m0 = blockIdx.x * 128, n0 = blockIdx.y * 128;
    const int tid = threadIdx.x, lane = tid & 63, wid = tid >> 6;
    const int wm = (wid >> 1) * 64, wn = (wid & 1) * 64;
    const int g = lane >> 4, c = lane & 15;

    f32x4 acc[4][4] = {};

    for (int kt = 0; kt < 16; ++kt) {
        const int k0 = kt * 64;
        for (int i = 0; i < 4; ++i) {
            int ch  = wid * 4 + i;
            int row = ch * 8 + (lane >> 3);
            int ls  = (lane & 7) ^ (row & 7);
            gload_lds16(WtO + (size_t)(n0 + row) * 1024 + k0 + ls * 8,
                        Bl + ch * 512);
            gload_lds16(Oh + (size_t)(m0 + row) * 1024 + k0 + ls * 8,
                        Al + ch * 512);
        }
        __syncthreads();
        for (int kc = 0; kc < 2; ++kc) {
            f16x8 af[4], bf[4];
            for (int mb = 0; mb < 4; ++mb) {
                int row = wm + mb * 16 + c;
                af[mb] = *(const f16x8*)&Al[row * 64 + ((kc * 4 + g) ^ (row & 7)) * 8];
            }
            for (int nb = 0; nb < 4; ++nb) {
                int row = wn + nb * 16 + c;
                bf[nb] = *(const f16x8*)&Bl[row * 64 + ((kc * 4 + g) ^ (row & 7)) * 8];
            }
            for (int mb = 0; mb < 4; ++mb)
                for (int nb = 0; nb < 4; ++nb)
                    acc[mb][nb] = __builtin_amdgcn_mfma_f32_16x16x32_f16(
                        af[mb], bf[nb], acc[mb][nb], 0, 0, 0);
        }
        __syncthreads();
    }
    for (int nb = 0; nb < 4; ++nb) {
        int n = n0 + wn + nb * 16 + c;
        float bv = bo[n];
        for (int mb = 0; mb < 4; ++mb)
            for (int r = 0; r < 4; ++r) {
                int m = m0 + wm + mb * 16 + g * 4 + r;
                out[(size_t)m * 1024 + n] = acc[mb][nb][r] + bv;
            }
    }
}

// ---------------------------------------------------------------------------
// Flash attention (r8/r10 config): swapped-operand 32x32, 4 waves x 32 q,
// KVBLK=128 double-buffered (64KB LDS, 2 blocks/CU), setprio around MFMA,
// exp2-domain softmax (Q pre-scaled), defer-max THR=8, in-register P packing,
// XCD-swizzled grid. __launch_bounds__(256,2): 8 waves/CU -> 256-reg budget,
// no accumulator spills (r9 lesson: 16 waves/CU caps at 128 regs -> spills).
// ---------------------------------------------------------------------------
__global__ __launch_bounds__(256, 2) void attn_kernel(
    const f16* __restrict__ qh, const f16* __restrict__ kh,
    const f16* __restrict__ vt, const unsigned char* __restrict__ maskp,
    const float* __restrict__ maskf, f16* __restrict__ Oh)
{
    __shared__ __align__(16) f16 Kl[2][128 * 64];   // [key][d]
    __shared__ __align__(16) f16 VTl[2][64 * 128];  // [hd][key]
    const int tid = threadIdx.x, lane = tid & 63, wid = tid >> 6;
    const int ql = lane & 31, hi = lane >> 5;
    // XCD-aware decode: blocks sharing (b,h) land on one XCD (1024 % 8 == 0)
    const int lg = ((blockIdx.x & 7) << 7) + (blockIdx.x >> 3);
    const int h = (lg >> 4) & 15, b = lg >> 8;
    const int q0 = (lg & 15) * 128 + wid * 32;

    const unsigned char* mrow = maskp + (size_t)b * S_;
    const float* mfrow = maskf + (size_t)b * S_;
    const size_t kbase  = (size_t)b * S_ * D_ + (size_t)h * HD_;   // kh [b][s][h][hd]
    const size_t vtbase = ((size_t)b * H_ + h) * (size_t)HD_ * S_; // vt [b][h][hd][s]

    // per-128-supertile liveness / partial-mask bits (16 supertiles)
    unsigned live = 0, part = 0;
    for (int t = 0; t < 16; ++t) {
        unsigned long long b0 = __ballot(mrow[t * 128 + lane] != 0);
        unsigned long long b1 = __ballot(mrow[t * 128 + 64 + lane] != 0);
        if (b0 != ~0ull || b1 != ~0ull) {
            live |= 1u << t;
            if (b0 | b1) part |= 1u << t;
        }
    }

    // Q fragments (B operand): row q = ql, d = dc*16 + hi*8 + e (pre-scaled)
    f16x8 qf[4];
    {
        const f16* qrow = qh + ((size_t)(b * S_ + q0 + ql) * H_ + h) * HD_;
        #pragma unroll
        for (int dc = 0; dc < 4; ++dc)
            qf[dc] = *(const f16x8*)&qrow[dc * 16 + hi * 8];
    }

    float m_ = -1e30f, l_ = 0.f;
    f32x16 accO[2] = {};

    // stage one 128-key supertile: K [128][64] + V^T [64][128]
    auto stage = [&](int kv0, int bb) {
        #pragma unroll
        for (int i = 0; i < 4; ++i) {
            int ch  = wid * 4 + i;                         // 16 chunks each
            int row = ch * 8 + (lane >> 3);                // K: key row 0..127
            int ls  = (lane & 7) ^ (row & 7);
            gload_lds16(kh + kbase + (size_t)(kv0 + row) * D_ + ls * 8,
                        &Kl[bb][ch * 512]);
            int hdr = ch * 4 + (lane >> 4);                // V: hd row 0..63
            int vs  = (lane & 15) ^ ((hdr & 7) << 1);
            gload_lds16(vt + vtbase + (size_t)hdr * S_ + kv0 + vs * 8,
                        &VTl[bb][ch * 512]);
        }
    };

    if (live) {
        int t = __builtin_ctz(live);
        stage(t * 128, 0);
        __syncthreads();
        int cur = 0;
        for (;;) {
            unsigned rem = live & (0xFFFFFFFEu << t);
            int tn = rem ? __builtin_ctz(rem) : 32;
            if (tn < 32) stage(tn * 128, cur ^ 1);  // prefetch next live supertile

            const int kv0 = t * 128;
            const f16* Kb = &Kl[cur][0];
            const f16* Vb = &VTl[cur][0];

            // S^T = K·Q^T (exp2 domain): sacc[ks] covers keys ks*32+crow(r,hi)
            f32x16 sacc[4] = {};
            __builtin_amdgcn_s_setprio(1);
            #pragma unroll
            for (int ks = 0; ks < 4; ++ks) {
                const int key = ks * 32 + ql;
                #pragma unroll
                for (int dc = 0; dc < 4; ++dc) {
                    int slot = (dc * 2 + hi) ^ (key & 7);
                    f16x8 kf = *(const f16x8*)&Kb[key * 64 + slot * 8];
                    sacc[ks] = __builtin_amdgcn_mfma_f32_32x32x16_f16(
                        kf, qf[dc], sacc[ks], 0, 0, 0);
                }
            }
            __builtin_amdgcn_s_setprio(0);
            if (part & (1u << t)) {                 // additive bias (tail only)
                #pragma unroll
                for (int ks = 0; ks < 4; ++ks)
                    #pragma unroll
                    for (int r = 0; r < 16; ++r) {
                        int key = kv0 + ks * 32 + (r & 3) + 8 * (r >> 2) + 4 * hi;
                        sacc[ks][r] += mfrow[key];
                    }
            }
            // tile max via max3 tree; defer-max: rescale only if growth > 8
            float mx;
            {
                float m0 = max3f(sacc[0][0], sacc[0][1], sacc[0][2]);
                float m1 = max3f(sacc[1][0], sacc[1][1], sacc[1][2]);
                float m2 = max3f(sacc[2][0], sacc[2][1], sacc[2][2]);
                float m3 = max3f(sacc[3][0], sacc[3][1], sacc[3][2]);
                #pragma unroll
                for (int r = 3; r < 15; r += 2) {
                    m0 = max3f(m0, sacc[0][r], sacc[0][r + 1]);
                    m1 = max3f(m1, sacc[1][r], sacc[1][r + 1]);
                    m2 = max3f(m2, sacc[2][r], sacc[2][r + 1]);
                    m3 = max3f(m3, sacc[3][r], sacc[3][r + 1]);
                }
                m0 = fmaxf(m0, sacc[0][15]); m1 = fmaxf(m1, sacc[1][15]);
                m2 = fmaxf(m2, sacc[2][15]); m3 = fmaxf(m3, sacc[3][15]);
                mx = max3f(m0, m1, m2);
                mx = fmaxf(mx, m3);
            }
            mx = pair_max(mx);
            if (__ballot(mx > m_ + 8.f)) {          // wave-uniform update
                float mnew = fmaxf(m_, mx);
                float alpha = exp2_hw(m_ - mnew);
                m_ = mnew;
                l_ *= alpha;
                #pragma unroll
                for (int blk = 0; blk < 2; ++blk)
                    #pragma unroll
                    for (int r = 0; r < 16; ++r) accO[blk][r] *= alpha;
            }
            // P = 2^(S - m) in place; row-sum
            float ts = 0.f;
            #pragma unroll
            for (int ks = 0; ks < 4; ++ks)
                #pragma unroll
                for (int r = 0; r < 16; ++r) {
                    float p = exp2_hw(sacc[ks][r] - m_);
                    sacc[ks][r] = p;
                    ts += p;
                }
            l_ += pair_sum(ts);

            // pack P (cvt_pkrtz + permlane32_swap) and PV: O^T += V^T · P^T
            #pragma unroll
            for (int ks = 0; ks < 4; ++ks) {
                unsigned Pq[4][2];
                #pragma unroll
                for (int j = 0; j < 4; ++j) {
                    Pq[j][0] = pkh(sacc[ks][4 * j + 0], sacc[ks][4 * j + 1]);
                    Pq[j][1] = pkh(sacc[ks][4 * j + 2], sacc[ks][4 * j + 3]);
                }
                #pragma unroll
                for (int kc = 0; kc < 2; ++kc) {
                    union { f16x8 v; unsigned u[4]; } pf;
                    u32x2 s0 = __builtin_amdgcn_permlane32_swap(Pq[2 * kc][0], Pq[2 * kc + 1][0], false, false);
                    u32x2 s1 = __builtin_amdgcn_permlane32_swap(Pq[2 * kc][1], Pq[2 * kc + 1][1], false, false);
                    pf.u[0] = s0[0]; pf.u[2] = s0[1];
                    pf.u[1] = s1[0]; pf.u[3] = s1[1];
                    const int s = ks * 2 + kc;      // 16-key slice 0..7
                    __builtin_amdgcn_s_setprio(1);
                    #pragma unroll
                    for (int blk = 0; blk < 2; ++blk) {
                        int hd = blk * 32 + ql;
                        int slot = (s * 2 + hi) ^ ((hd & 7) << 1);
                        f16x8 vtf = *(const f16x8*)&Vb[hd * 128 + slot * 8];
                        accO[blk] = __builtin_amdgcn_mfma_f32_32x32x16_f16(
                            vtf, pf.v, accO[blk], 0, 0, 0);
                    }
                    __builtin_amdgcn_s_setprio(0);
                }
            }
            __syncthreads();                        // next tile staged + buf free
            cur ^= 1;
            if (tn == 32) break;
            t = tn;
        }
    }
    // epilogue: O^T[hd=crow(r,hi)+32blk][q=ql] / l -> Oh[b][s][h][hd]
    const float invl = (l_ > 0.f) ? 1.f / l_ : 0.f;
    f16* orow = Oh + ((size_t)(b * S_ + q0 + ql) * H_ + h) * HD_;
    #pragma unroll
    for (int blk = 0; blk < 2; ++blk)
        #pragma unroll
        for (int j = 0; j < 4; ++j) {
            f16x4 o;
            #pragma unroll
            for (int tt = 0; tt < 4; ++tt)
                o[tt] = (f16)(accO[blk][4 * j + tt] * invl);
            *(f16x4*)&orow[blk * 32 + 4 * hi + 8 * j] = o;
        }
}

// ---------------------------------------------------------------------------
extern "C" void kernel_launch(void* const* d_in, const int* in_sizes, int n_in,
                              void* d_out, int out_size, void* d_ws, size_t ws_size,
                              hipStream_t stream)
{
    const float* q    = (const float*)d_in[0];
    const float* k    = (const float*)d_in[1];
    const float* v    = (const float*)d_in[2];
    const unsigned char* mask = (const unsigned char*)d_in[3];
    const float* Wq   = (const float*)d_in[4];
    const float* bq   = (const float*)d_in[5];
    const float* Wk   = (const float*)d_in[6];
    const float* bk   = (const float*)d_in[7];
    const float* Wv   = (const float*)d_in[8];
    const float* bv   = (const float*)d_in[9];
    const float* Wo   = (const float*)d_in[10];
    const float* bo   = (const float*)d_in[11];
    float* out        = (float*)d_out;

    // ws layout (MB): Wt 0-8 | qh 8-24 | kh 24-40 | vt 40-56 | Oh 56-72 | nm/mf 72+
    char* ws = (char*)d_ws;
    const size_t MB = 1048576;
    f16* Wt  = (f16*)ws;
    f16* qh  = (f16*)(ws + 8 * MB);
    f16* khp = (f16*)(ws + 24 * MB);
    f16* vtp = (f16*)(ws + 40 * MB);
    f16* Ohp = (f16*)(ws + 56 * MB);
    unsigned char* nm = (unsigned char*)(ws + 72 * MB);
    float* mf = (float*)(ws + 72 * MB + 8192);

    mask_norm_kernel<<<1, 256, 0, stream>>>(mask, nm, mf);
    wconv_kernel<<<dim3(16, 16, 4), 256, 0, stream>>>(Wq, Wk, Wv, Wo, Wt);
    gemm_qkv3_kernel<<<dim3(64, 8), 256, 0, stream>>>(q, k, v, Wt, bq, bk, bv, qh);
    attn_kernel<<<1024, 256, 0, stream>>>(qh, khp, vtp, nm, mf, Ohp);
    gemm_out_kernel<<<dim3(64, 8), 256, 0, stream>>>(Ohp, Wt + (size_t)3 * D_ * D_, bo, out);
}

// Round 15
// 228.220 us; speedup vs baseline: 1.8504x; 1.8504x over previous
//
#include <hip/hip_runtime.h>
#include <hip/hip_fp16.h>
#include <cstdint>
#include <cstddef>

// Dims (fixed by the reference)
#define B_  4
#define S_  2048
#define D_  1024
#define H_  16
#define HD_ 64
#define TAU_ 0.125f
// TAU * log2(e), applied in f32 in the Q-projection epilogue (exp2 domain)
#define QSCALE_ 0.18033688011112042f

typedef _Float16 f16;
typedef __attribute__((ext_vector_type(8)))  _Float16 f16x8;
typedef __attribute__((ext_vector_type(4)))  _Float16 f16x4;
typedef __attribute__((ext_vector_type(2)))  __fp16   fp16x2_b;   // builtin ret type
typedef __attribute__((ext_vector_type(4)))  float    f32x4;
typedef __attribute__((ext_vector_type(16))) float    f32x16;
typedef __attribute__((ext_vector_type(2)))  unsigned u32x2;

// Async global->LDS, 16B per lane. LDS dest must be the WAVE-UNIFORM chunk
// base; HW writes lane l at base + l*16 (m97 pattern). Global addr is per-lane.
__device__ __forceinline__ void gload_lds16(const void* g, void* l) {
    __builtin_amdgcn_global_load_lds(
        (const __attribute__((address_space(1))) unsigned int*)g,
        (__attribute__((address_space(3)))       unsigned int*)l,
        16, 0, 0);
}

__device__ __forceinline__ unsigned pkh(float a, float b) {
    fp16x2_b h = __builtin_amdgcn_cvt_pkrtz(a, b);
    return __builtin_bit_cast(unsigned, h);
}

// raw v_exp_f32 = 2^x
__device__ __forceinline__ float exp2_hw(float x) {
    float r;
    asm("v_exp_f32 %0, %1" : "=v"(r) : "v"(x));
    return r;
}

__device__ __forceinline__ float max3f(float a, float b, float c) {
    float r;
    asm("v_max3_f32 %0, %1, %2, %3" : "=v"(r) : "v"(a), "v"(b), "v"(c));
    return r;
}

// permlane32_swap(x,x): {out0,out1} = {own,partner} (order differs per half),
// so max/sum over both gives the cross-half combine without a select.
__device__ __forceinline__ float pair_max(float x) {
    unsigned xu = __builtin_bit_cast(unsigned, x);
    u32x2 r = __builtin_amdgcn_permlane32_swap(xu, xu, false, false);
    return fmaxf(__builtin_bit_cast(float, r[0]), __builtin_bit_cast(float, r[1]));
}
__device__ __forceinline__ float pair_sum(float x) {
    unsigned xu = __builtin_bit_cast(unsigned, x);
    u32x2 r = __builtin_amdgcn_permlane32_swap(xu, xu, false, false);
    return __builtin_bit_cast(float, r[0]) + __builtin_bit_cast(float, r[1]);
}

// ---------------------------------------------------------------------------
// Mask normalization: detect physical dtype (bool bytes / int32 / float32)
// from the first 8192 bytes; write canonical bytes AND additive f32 bias.
// ---------------------------------------------------------------------------
__global__ __launch_bounds__(256) void mask_norm_kernel(
    const unsigned char* __restrict__ mp, unsigned char* __restrict__ nm,
    float* __restrict__ mf)
{
    __shared__ int flags[3];
    const int tid = threadIdx.x;
    if (tid < 3) flags[tid] = 0;
    __syncthreads();
    int loc0 = 0, loc1 = 0, loc2 = 0;
    for (int i = 0; i < 32; ++i) {
        int off = tid * 32 + i;
        unsigned char v = mp[off];
        if (v) {
            int m = off & 3;
            if (m == 0) loc0 = 1;
            else if (m == 1) loc1 = 1;
            else loc2 = 1;
        }
    }
    if (loc0) atomicOr(&flags[0], 1);
    if (loc1) atomicOr(&flags[1], 1);
    if (loc2) atomicOr(&flags[2], 1);
    __syncthreads();
    const int mode = flags[1] ? 0 : (flags[2] ? 2 : (flags[0] ? 1 : 0));
    for (int i = 0; i < 32; ++i) {
        int idx = tid * 32 + i;            // 8192 mask elements
        unsigned char r;
        if (mode == 0)      r = mp[idx] ? 1 : 0;
        else if (mode == 1) r = ((const int*)mp)[idx] ? 1 : 0;
        else                r = (((const float*)mp)[idx] != 0.f) ? 1 : 0;
        nm[idx] = r;
        mf[idx] = r ? -1e30f : 0.f;
    }
}

// ---------------------------------------------------------------------------
// W[k][n] fp32 -> Wt[n][k] fp16 (transpose via padded LDS tiles).
// ---------------------------------------------------------------------------
__global__ __launch_bounds__(256) void wconv_kernel(
    const float* __restrict__ W0, const float* __restrict__ W1,
    const float* __restrict__ W2, const float* __restrict__ W3,
    f16* __restrict__ Wt)
{
    __shared__ float T[64][65];
    const int z = blockIdx.z;
    const float* W = (z == 0) ? W0 : (z == 1) ? W1 : (z == 2) ? W2 : W3;
    f16* out = Wt + (size_t)z * D_ * D_;
    const int n0 = blockIdx.x * 64, k0 = blockIdx.y * 64;
    const int tid = threadIdx.x;
    for (int j = 0; j < 4; ++j) {
        int idx = j * 256 + tid;           // 1024 float4 chunks
        int r = idx >> 4, c4 = idx & 15;
        float4 v = *(const float4*)&W[(size_t)(k0 + r) * D_ + n0 + c4 * 4];
        T[r][c4 * 4 + 0] = v.x; T[r][c4 * 4 + 1] = v.y;
        T[r][c4 * 4 + 2] = v.z; T[r][c4 * 4 + 3] = v.w;
    }
    __syncthreads();
    for (int j = 0; j < 16; ++j) {
        int idx = j * 256 + tid;           // 4096 elems
        int nl = idx >> 6, kl = idx & 63;
        out[(size_t)(n0 + nl) * D_ + k0 + kl] = (f16)T[kl][nl];
    }
}

// ---------------------------------------------------------------------------
// QKV projection GEMM (r10 best variant): fp32 A staged DIRECTLY in LDS via
// global_load_lds (32KB f32 tile, 16-slot XOR swizzle, pre-swizzled source)
// + B f16 via global_load_lds (16KB). f32->f16 RTN at fragment read.
// 48KB LDS. z: 0=Q (QSCALE), 1=K, 2=V (transposed [b][h][hd][s]).
// ---------------------------------------------------------------------------
__global__ __launch_bounds__(256) void gemm_qkvf_kernel(
    const float* __restrict__ q, const float* __restrict__ k,
    const float* __restrict__ v, const f16* __restrict__ Wt,
    const float* __restrict__ bq, const float* __restrict__ bk,
    const float* __restrict__ bv, f16* __restrict__ outbase)
{
    __shared__ __align__(16) float Al[128 * 64];   // 32KB f32
    __shared__ __align__(16) f16  Bl[128 * 64];    // 16KB f16
    const int z = blockIdx.z;
    const float* A  = (z == 0) ? q  : (z == 1) ? k  : v;
    const float* bi = (z == 0) ? bq : (z == 1) ? bk : bv;
    const f16*  W   = Wt + (size_t)z * D_ * D_;
    f16* Cp         = outbase + (size_t)z * S_ * B_ * D_;
    const float oscale = (z == 0) ? QSCALE_ : 1.f;
    const int outmode  = (z == 2) ? 1 : 0;
    const int m0 = blockIdx.x * 128, n0 = blockIdx.y * 128;
    const int tid = threadIdx.x, lane = tid & 63, wid = tid >> 6;
    const int wm = (wid >> 1) * 64, wn = (wid & 1) * 64;
    const int g = lane >> 4, c = lane & 15;

    f32x4 acc[4][4] = {};

    for (int kt = 0; kt < 16; ++kt) {
        const int k0 = kt * 64;
        // --- stage B (f16 Wt rows n0..+127, cols k0..+63), 8-slot swizzle ---
        for (int i = 0; i < 4; ++i) {
            int ch  = wid * 4 + i;                 // 16 chunks of 1024B
            int row = ch * 8 + (lane >> 3);
            int ls  = (lane & 7) ^ (row & 7);
            gload_lds16(W + (size_t)(n0 + row) * 1024 + k0 + ls * 8,
                        Bl + ch * 512);
        }
        // --- stage A (f32 rows m0..+127, cols k0..+63), 16-slot swizzle ---
        for (int i = 0; i < 8; ++i) {
            int ch  = wid * 8 + i;                 // 32 chunks of 1024B
            int row = ch * 4 + (lane >> 4);        // 4 rows per chunk
            int ls  = (lane & 15) ^ (row & 15);    // 16B slot of 4 f32
            gload_lds16(A + (size_t)(m0 + row) * 1024 + k0 + ls * 4,
                        Al + ch * 256);
        }
        __syncthreads();
        // --- compute: 2 k-chunks of 32, 4x4 16x16 frags per wave ---
        for (int kc = 0; kc < 2; ++kc) {
            f16x8 af[4], bf[4];
            for (int mb = 0; mb < 4; ++mb) {
                int row = wm + mb * 16 + c;
                int sl  = kc * 8 + g * 2;          // logical 16B slot (f32)
                f32x4 a0 = *(const f32x4*)&Al[row * 64 + ((sl)     ^ (row & 15)) * 4];
                f32x4 a1 = *(const f32x4*)&Al[row * 64 + ((sl + 1) ^ (row & 15)) * 4];
                f16x8 hfr;
                hfr[0] = (f16)a0[0]; hfr[1] = (f16)a0[1];
                hfr[2] = (f16)a0[2]; hfr[3] = (f16)a0[3];
                hfr[4] = (f16)a1[0]; hfr[5] = (f16)a1[1];
                hfr[6] = (f16)a1[2]; hfr[7] = (f16)a1[3];
                af[mb] = hfr;
            }
            for (int nb = 0; nb < 4; ++nb) {
                int row = wn + nb * 16 + c;
                bf[nb] = *(const f16x8*)&Bl[row * 64 + ((kc * 4 + g) ^ (row & 7)) * 8];
            }
            for (int mb = 0; mb < 4; ++mb)
                for (int nb = 0; nb < 4; ++nb)
                    acc[mb][nb] = __builtin_amdgcn_mfma_f32_16x16x32_f16(
                        af[mb], bf[nb], acc[mb][nb], 0, 0, 0);
        }
        __syncthreads();
    }
    // --- epilogue: C/D layout col=lane&15, row=(lane>>4)*4+reg (m89) ---
    for (int nb = 0; nb < 4; ++nb) {
        int n = n0 + wn + nb * 16 + c;
        float bv2 = bi[n];
        for (int mb = 0; mb < 4; ++mb)
            for (int r = 0; r < 4; ++r) {
                int m = m0 + wm + mb * 16 + g * 4 + r;
                float val = (acc[mb][nb][r] + bv2) * oscale;
                if (outmode == 1) {
                    // [b][h][hd][s]  (b=m>>11, s=m&2047, h=n>>6, hd=n&63)
                    Cp[(((size_t)(m >> 11) * H_ + (n >> 6)) * HD_ + (n & 63)) * S_ + (m & 2047)] = (f16)val;
                } else {
                    Cp[(size_t)m * 1024 + n] = (f16)val;
                }
            }
    }
}

// ---------------------------------------------------------------------------
// Output projection: Oh (f16) @ Wo^T + bo -> fp32 out. f16 A via
// global_load_lds, 32KB LDS, 128x128 structure (r10 serial form).
// ---------------------------------------------------------------------------
__global__ __launch_bounds__(256) void gemm_out_kernel(
    const f16* __restrict__ Oh, const f16* __restrict__ WtO,
    const float* __restrict__ bo, float* __restrict__ out)
{
    __shared__ __align__(16) f16 Al[128 * 64];
    __shared__ __align__(16) f16 Bl[128 * 64];
    const int m0 = blockIdx.x * 128, n0 = blockIdx.y * 128;
    const int tid = threadIdx.x, lane = tid & 63, wid = tid >> 6;
    const int wm = (wid >> 1) * 64, wn = (wid & 1) * 64;
    const int g = lane >> 4, c = lane & 15;

    f32x4 acc[4][4] = {};

    for (int kt = 0; kt < 16; ++kt) {
        const int k0 = kt * 64;
        for (int i = 0; i < 4; ++i) {
            int ch  = wid * 4 + i;
            int row = ch * 8 + (lane >> 3);
            int ls  = (lane & 7) ^ (row & 7);
            gload_lds16(WtO + (size_t)(n0 + row) * 1024 + k0 + ls * 8,
                        Bl + ch * 512);
            gload_lds16(Oh + (size_t)(m0 + row) * 1024 + k0 + ls * 8,
                        Al + ch * 512);
        }
        __syncthreads();
        for (int kc = 0; kc < 2; ++kc) {
            f16x8 af[4], bf[4];
            for (int mb = 0; mb < 4; ++mb) {
                int row = wm + mb * 16 + c;
                af[mb] = *(const f16x8*)&Al[row * 64 + ((kc * 4 + g) ^ (row & 7)) * 8];
            }
            for (int nb = 0; nb < 4; ++nb) {
                int row = wn + nb * 16 + c;
                bf[nb] = *(const f16x8*)&Bl[row * 64 + ((kc * 4 + g) ^ (row & 7)) * 8];
            }
            for (int mb = 0; mb < 4; ++mb)
                for (int nb = 0; nb < 4; ++nb)
                    acc[mb][nb] = __builtin_amdgcn_mfma_f32_16x16x32_f16(
                        af[mb], bf[nb], acc[mb][nb], 0, 0, 0);
        }
        __syncthreads();
    }
    for (int nb = 0; nb < 4; ++nb) {
        int n = n0 + wn + nb * 16 + c;
        float bv = bo[n];
        for (int mb = 0; mb < 4; ++mb)
            for (int r = 0; r < 4; ++r) {
                int m = m0 + wm + mb * 16 + g * 4 + r;
                out[(size_t)m * 1024 + n] = acc[mb][nb][r] + bv;
            }
    }
}

// ---------------------------------------------------------------------------
// Flash attention (r10 config + V^T swizzle fix): swapped-operand 32x32,
// 4 waves x 32 q, KVBLK=128 double-buffered (64KB LDS), setprio around MFMA,
// exp2-domain softmax, defer-max THR=8, in-register P packing, XCD grid.
// V^T tile now uses full 4-bit XOR swizzle ^(hd&15) on BOTH sides (DMA
// source + read) -- the old ^((hd&7)<<1) spanned only even slots -> 4 of 8
// bank-groups -> the constant 7.3e6 SQ_LDS_BANK_CONFLICT.
// ---------------------------------------------------------------------------
__global__ __launch_bounds__(256, 2) void attn_kernel(
    const f16* __restrict__ qh, const f16* __restrict__ kh,
    const f16* __restrict__ vt, const unsigned char* __restrict__ maskp,
    const float* __restrict__ maskf, f16* __restrict__ Oh)
{
    __shared__ __align__(16) f16 Kl[2][128 * 64];   // [key][d]
    __shared__ __align__(16) f16 VTl[2][64 * 128];  // [hd][key]
    const int tid = threadIdx.x, lane = tid & 63, wid = tid >> 6;
    const int ql = lane & 31, hi = lane >> 5;
    // XCD-aware decode: blocks sharing (b,h) land on one XCD (1024 % 8 == 0)
    const int lg = ((blockIdx.x & 7) << 7) + (blockIdx.x >> 3);
    const int h = (lg >> 4) & 15, b = lg >> 8;
    const int q0 = (lg & 15) * 128 + wid * 32;

    const unsigned char* mrow = maskp + (size_t)b * S_;
    const float* mfrow = maskf + (size_t)b * S_;
    const size_t kbase  = (size_t)b * S_ * D_ + (size_t)h * HD_;   // kh [b][s][h][hd]
    const size_t vtbase = ((size_t)b * H_ + h) * (size_t)HD_ * S_; // vt [b][h][hd][s]

    // per-128-supertile liveness / partial-mask bits (16 supertiles)
    unsigned live = 0, part = 0;
    for (int t = 0; t < 16; ++t) {
        unsigned long long b0 = __ballot(mrow[t * 128 + lane] != 0);
        unsigned long long b1 = __ballot(mrow[t * 128 + 64 + lane] != 0);
        if (b0 != ~0ull || b1 != ~0ull) {
            live |= 1u << t;
            if (b0 | b1) part |= 1u << t;
        }
    }

    // Q fragments (B operand): row q = ql, d = dc*16 + hi*8 + e (pre-scaled)
    f16x8 qf[4];
    {
        const f16* qrow = qh + ((size_t)(b * S_ + q0 + ql) * H_ + h) * HD_;
        #pragma unroll
        for (int dc = 0; dc < 4; ++dc)
            qf[dc] = *(const f16x8*)&qrow[dc * 16 + hi * 8];
    }

    float m_ = -1e30f, l_ = 0.f;
    f32x16 accO[2] = {};

    // stage one 128-key supertile: K [128][64] + V^T [64][128]
    auto stage = [&](int kv0, int bb) {
        #pragma unroll
        for (int i = 0; i < 4; ++i) {
            int ch  = wid * 4 + i;                         // 16 chunks each
            int row = ch * 8 + (lane >> 3);                // K: key row 0..127
            int ls  = (lane & 7) ^ (row & 7);
            gload_lds16(kh + kbase + (size_t)(kv0 + row) * D_ + ls * 8,
                        &Kl[bb][ch * 512]);
            int hdr = ch * 4 + (lane >> 4);                // V: hd row 0..63
            int vs  = (lane & 15) ^ (hdr & 15);            // full 4-bit swizzle
            gload_lds16(vt + vtbase + (size_t)hdr * S_ + kv0 + vs * 8,
                        &VTl[bb][ch * 512]);
        }
    };

    if (live) {
        int t = __builtin_ctz(live);
        stage(t * 128, 0);
        __syncthreads();
        int cur = 0;
        for (;;) {
            unsigned rem = live & (0xFFFFFFFEu << t);
            int tn = rem ? __builtin_ctz(rem) : 32;
            if (tn < 32) stage(tn * 128, cur ^ 1);  // prefetch next live supertile

            const int kv0 = t * 128;
            const f16* Kb = &Kl[cur][0];
            const f16* Vb = &VTl[cur][0];

            // S^T = K·Q^T (exp2 domain): sacc[ks] covers keys ks*32+crow(r,hi)
            f32x16 sacc[4] = {};
            __builtin_amdgcn_s_setprio(1);
            #pragma unroll
            for (int ks = 0; ks < 4; ++ks) {
                const int key = ks * 32 + ql;
                #pragma unroll
                for (int dc = 0; dc < 4; ++dc) {
                    int slot = (dc * 2 + hi) ^ (key & 7);
                    f16x8 kf = *(const f16x8*)&Kb[key * 64 + slot * 8];
                    sacc[ks] = __builtin_amdgcn_mfma_f32_32x32x16_f16(
                        kf, qf[dc], sacc[ks], 0, 0, 0);
                }
            }
            __builtin_amdgcn_s_setprio(0);
            if (part & (1u << t)) {                 // additive bias (tail only)
                #pragma unroll
                for (int ks = 0; ks < 4; ++ks)
                    #pragma unroll
                    for (int r = 0; r < 16; ++r) {
                        int key = kv0 + ks * 32 + (r & 3) + 8 * (r >> 2) + 4 * hi;
                        sacc[ks][r] += mfrow[key];
                    }
            }
            // tile max via max3 tree; defer-max: rescale only if growth > 8
            float mx;
            {
                float m0 = max3f(sacc[0][0], sacc[0][1], sacc[0][2]);
                float m1 = max3f(sacc[1][0], sacc[1][1], sacc[1][2]);
                float m2 = max3f(sacc[2][0], sacc[2][1], sacc[2][2]);
                float m3 = max3f(sacc[3][0], sacc[3][1], sacc[3][2]);
                #pragma unroll
                for (int r = 3; r < 15; r += 2) {
                    m0 = max3f(m0, sacc[0][r], sacc[0][r + 1]);
                    m1 = max3f(m1, sacc[1][r], sacc[1][r + 1]);
                    m2 = max3f(m2, sacc[2][r], sacc[2][r + 1]);
                    m3 = max3f(m3, sacc[3][r], sacc[3][r + 1]);
                }
                m0 = fmaxf(m0, sacc[0][15]); m1 = fmaxf(m1, sacc[1][15]);
                m2 = fmaxf(m2, sacc[2][15]); m3 = fmaxf(m3, sacc[3][15]);
                mx = max3f(m0, m1, m2);
                mx = fmaxf(mx, m3);
            }
            mx = pair_max(mx);
            if (__ballot(mx > m_ + 8.f)) {          // wave-uniform update
                float mnew = fmaxf(m_, mx);
                float alpha = exp2_hw(m_ - mnew);
                m_ = mnew;
                l_ *= alpha;
                #pragma unroll
                for (int blk = 0; blk < 2; ++blk)
                    #pragma unroll
                    for (int r = 0; r < 16; ++r) accO[blk][r] *= alpha;
            }
            // P = 2^(S - m) in place; row-sum
            float ts = 0.f;
            #pragma unroll
            for (int ks = 0; ks < 4; ++ks)
                #pragma unroll
                for (int r = 0; r < 16; ++r) {
                    float p = exp2_hw(sacc[ks][r] - m_);
                    sacc[ks][r] = p;
                    ts += p;
                }
            l_ += pair_sum(ts);

            // pack P (cvt_pkrtz + permlane32_swap) and PV: O^T += V^T · P^T
            #pragma unroll
            for (int ks = 0; ks < 4; ++ks) {
                unsigned Pq[4][2];
                #pragma unroll
                for (int j = 0; j < 4; ++j) {
                    Pq[j][0] = pkh(sacc[ks][4 * j + 0], sacc[ks][4 * j + 1]);
                    Pq[j][1] = pkh(sacc[ks][4 * j + 2], sacc[ks][4 * j + 3]);
                }
                #pragma unroll
                for (int kc = 0; kc < 2; ++kc) {
                    union { f16x8 v; unsigned u[4]; } pf;
                    u32x2 s0 = __builtin_amdgcn_permlane32_swap(Pq[2 * kc][0], Pq[2 * kc + 1][0], false, false);
                    u32x2 s1 = __builtin_amdgcn_permlane32_swap(Pq[2 * kc][1], Pq[2 * kc + 1][1], false, false);
                    pf.u[0] = s0[0]; pf.u[2] = s0[1];
                    pf.u[1] = s1[0]; pf.u[3] = s1[1];
                    const int s = ks * 2 + kc;      // 16-key slice 0..7
                    __builtin_amdgcn_s_setprio(1);
                    #pragma unroll
                    for (int blk = 0; blk < 2; ++blk) {
                        int hd = blk * 32 + ql;
                        int slot = (s * 2 + hi) ^ (hd & 15);   // full 4-bit swizzle
                        f16x8 vtf = *(const f16x8*)&Vb[hd * 128 + slot * 8];
                        accO[blk] = __builtin_amdgcn_mfma_f32_32x32x16_f16(
                            vtf, pf.v, accO[blk], 0, 0, 0);
                    }
                    __builtin_amdgcn_s_setprio(0);
                }
            }
            __syncthreads();                        // next tile staged + buf free
            cur ^= 1;
            if (tn == 32) break;
            t = tn;
        }
    }
    // epilogue: O^T[hd=crow(r,hi)+32blk][q=ql] / l -> Oh[b][s][h][hd]
    const float invl = (l_ > 0.f) ? 1.f / l_ : 0.f;
    f16* orow = Oh + ((size_t)(b * S_ + q0 + ql) * H_ + h) * HD_;
    #pragma unroll
    for (int blk = 0; blk < 2; ++blk)
        #pragma unroll
        for (int j = 0; j < 4; ++j) {
            f16x4 o;
            #pragma unroll
            for (int tt = 0; tt < 4; ++tt)
                o[tt] = (f16)(accO[blk][4 * j + tt] * invl);
            *(f16x4*)&orow[blk * 32 + 4 * hi + 8 * j] = o;
        }
}

// ---------------------------------------------------------------------------
extern "C" void kernel_launch(void* const* d_in, const int* in_sizes, int n_in,
                              void* d_out, int out_size, void* d_ws, size_t ws_size,
                              hipStream_t stream)
{
    const float* q    = (const float*)d_in[0];
    const float* k    = (const float*)d_in[1];
    const float* v    = (const float*)d_in[2];
    const unsigned char* mask = (const unsigned char*)d_in[3];
    const float* Wq   = (const float*)d_in[4];
    const float* bq   = (const float*)d_in[5];
    const float* Wk   = (const float*)d_in[6];
    const float* bk   = (const float*)d_in[7];
    const float* Wv   = (const float*)d_in[8];
    const float* bv   = (const float*)d_in[9];
    const float* Wo   = (const float*)d_in[10];
    const float* bo   = (const float*)d_in[11];
    float* out        = (float*)d_out;

    // ws layout (MB): Wt 0-8 | qh 8-24 | kh 24-40 | vt 40-56 | Oh 56-72 | nm/mf 72+
    char* ws = (char*)d_ws;
    const size_t MB = 1048576;
    f16* Wt  = (f16*)ws;
    f16* qh  = (f16*)(ws + 8 * MB);
    f16* khp = (f16*)(ws + 24 * MB);
    f16* vtp = (f16*)(ws + 40 * MB);
    f16* Ohp = (f16*)(ws + 56 * MB);
    unsigned char* nm = (unsigned char*)(ws + 72 * MB);
    float* mf = (float*)(ws + 72 * MB + 8192);

    mask_norm_kernel<<<1, 256, 0, stream>>>(mask, nm, mf);
    wconv_kernel<<<dim3(16, 16, 4), 256, 0, stream>>>(Wq, Wk, Wv, Wo, Wt);
    gemm_qkvf_kernel<<<dim3(64, 8, 3), 256, 0, stream>>>(q, k, v, Wt, bq, bk, bv, qh);
    attn_kernel<<<1024, 256, 0, stream>>>(qh, khp, vtp, nm, mf, Ohp);
    gemm_out_kernel<<<dim3(64, 8), 256, 0, stream>>>(Ohp, Wt + (size_t)3 * D_ * D_, bo, out);
}